// Round 1
// baseline (2790.504 us; speedup 1.0000x reference)
//
#include <hip/hip_runtime.h>
#include <math.h>

#define N_NODES 100000
#define N_EDGES 3200000
#define D_FEAT 64
#define CLAMP_V 20.0f

// ---------------------------------------------------------------------------
// Kernel 1: zero the output accumulator (d_out is poisoned 0xAA pre-launch).
// ---------------------------------------------------------------------------
__global__ void zero_kernel(float4* __restrict__ out, int n4) {
    int i = blockIdx.x * blockDim.x + threadIdx.x;
    if (i < n4) out[i] = make_float4(0.f, 0.f, 0.f, 0.f);
}

// ---------------------------------------------------------------------------
// Kernel 2: COO scatter.  16 lanes per edge; lane q handles features
// [4q, 4q+4) as one float4 gather + 4 float atomicAdds.
// ---------------------------------------------------------------------------
__global__ void scatter_kernel(const float* __restrict__ x,
                               const int* __restrict__ esrc,
                               const int* __restrict__ edst,
                               const float* __restrict__ ew,
                               float* __restrict__ out) {
    long long tid = (long long)blockIdx.x * blockDim.x + threadIdx.x;
    int edge = (int)(tid >> 4);
    int q    = (int)(tid & 15);
    if (edge >= N_EDGES) return;

    int   s = esrc[edge];
    int   d = edst[edge];
    float w = ew[edge];

    const float4* xrow = (const float4*)(x + (size_t)s * D_FEAT);
    float4 v = xrow[q];

    float* orow = out + (size_t)d * D_FEAT + q * 4;
    atomicAdd(orow + 0, w * v.x);
    atomicAdd(orow + 1, w * v.y);
    atomicAdd(orow + 2, w * v.z);
    atomicAdd(orow + 3, w * v.w);
}

// ---------------------------------------------------------------------------
// Kernel 3: epilogue — nan_to_num(nan=0, posinf=1e6, neginf=-1e6) + clamp.
// fminf/fmaxf against +-CLAMP_V already maps +-inf to +-CLAMP_V; NaN needs
// the explicit check (fminf(NaN, c) returns c, which would be wrong sign-wise
// only for NaN; ref maps NaN -> 0).
// ---------------------------------------------------------------------------
__global__ void epilogue_kernel(float4* __restrict__ out, int n4) {
    int i = blockIdx.x * blockDim.x + threadIdx.x;
    if (i >= n4) return;
    float4 v = out[i];
    float* p = &v.x;
#pragma unroll
    for (int k = 0; k < 4; ++k) {
        float f = p[k];
        if (isnan(f)) f = 0.0f;
        f = fminf(fmaxf(f, -CLAMP_V), CLAMP_V);
        p[k] = f;
    }
    out[i] = v;
}

extern "C" void kernel_launch(void* const* d_in, const int* in_sizes, int n_in,
                              void* d_out, int out_size, void* d_ws, size_t ws_size,
                              hipStream_t stream) {
    // inputs: 0=t[1] f32, 1=x[N*D] f32, 2=edge_src i32, 3=edge_dst i32, 4=edge_w f32
    const float* x    = (const float*)d_in[1];
    const int*   esrc = (const int*)d_in[2];
    const int*   edst = (const int*)d_in[3];
    const float* ew   = (const float*)d_in[4];
    float*       out  = (float*)d_out;

    const int n  = N_NODES * D_FEAT;   // 6,400,000
    const int n4 = n / 4;              // 1,600,000

    {
        int threads = 256;
        int blocks = (n4 + threads - 1) / threads;
        zero_kernel<<<blocks, threads, 0, stream>>>((float4*)out, n4);
    }
    {
        long long total = (long long)N_EDGES * 16;  // 51.2M threads
        int threads = 256;
        long long blocks = (total + threads - 1) / threads;
        scatter_kernel<<<(int)blocks, threads, 0, stream>>>(x, esrc, edst, ew, out);
    }
    {
        int threads = 256;
        int blocks = (n4 + threads - 1) / threads;
        epilogue_kernel<<<blocks, threads, 0, stream>>>((float4*)out, n4);
    }
}

// Round 2
// 850.887 us; speedup vs baseline: 3.2795x; 3.2795x over previous
//
#include <hip/hip_runtime.h>
#include <math.h>

#define N_NODES 100000
#define N_EDGES 3200000
#define D_FEAT 64
#define CLAMP_V 20.0f
#define SCAN_T 1024

// ===========================================================================
// CSR-by-dst build + gather SpMM (no feature atomics).
// d_ws layout: counts[N] | starts[N+1] | cursors[N] | ssrc[E] | sw[E]
// ===========================================================================

__global__ void zero_counts_kernel(int* __restrict__ counts, int n) {
    int i = blockIdx.x * blockDim.x + threadIdx.x;
    if (i < n) counts[i] = 0;
}

__global__ void hist_kernel(const int* __restrict__ edst, int* __restrict__ counts) {
    int e = blockIdx.x * blockDim.x + threadIdx.x;
    if (e < N_EDGES) atomicAdd(&counts[edst[e]], 1);
}

// Single-block exclusive scan over counts[N] -> starts[N+1], also seeds cursors.
__global__ void scan_kernel(const int* __restrict__ counts,
                            int* __restrict__ starts,
                            int* __restrict__ cursors) {
    __shared__ int sums[SCAN_T];
    int t = threadIdx.x;
    const int chunk = (N_NODES + SCAN_T - 1) / SCAN_T;
    int beg = min(t * chunk, N_NODES);
    int end = min(beg + chunk, N_NODES);
    int s = 0;
    for (int i = beg; i < end; ++i) s += counts[i];
    int incl = s;
    sums[t] = incl;
    __syncthreads();
    for (int off = 1; off < SCAN_T; off <<= 1) {
        int add = (t >= off) ? sums[t - off] : 0;
        __syncthreads();
        incl += add;
        sums[t] = incl;
        __syncthreads();
    }
    int run = incl - s;  // exclusive prefix of this thread's chunk
    for (int i = beg; i < end; ++i) {
        starts[i] = run;
        cursors[i] = run;
        run += counts[i];
    }
    if (t == SCAN_T - 1) starts[N_NODES] = incl;  // total (= N_EDGES)
}

__global__ void bucket_kernel(const int* __restrict__ esrc,
                              const int* __restrict__ edst,
                              const float* __restrict__ ew,
                              int* __restrict__ cursors,
                              int* __restrict__ ssrc,
                              float* __restrict__ sw) {
    int e = blockIdx.x * blockDim.x + threadIdx.x;
    if (e >= N_EDGES) return;
    int d = edst[e];
    int pos = atomicAdd(&cursors[d], 1);
    ssrc[pos] = esrc[e];
    sw[pos] = ew[e];
}

// One wave per destination node; lane = feature column. Coalesced 256B row
// reads of x (L3-resident); edge (src,w) loads are wave-uniform. Epilogue
// (nan_to_num + clamp) fused.
__global__ void gather_kernel(const float* __restrict__ x,
                              const int* __restrict__ ssrc,
                              const float* __restrict__ sw,
                              const int* __restrict__ starts,
                              float* __restrict__ out) {
    int node = blockIdx.x * (blockDim.x >> 6) + (threadIdx.x >> 6);
    int lane = threadIdx.x & 63;
    if (node >= N_NODES) return;
    int beg = starts[node];
    int end = starts[node + 1];
    float acc = 0.0f;
    int e = beg;
    // manual unroll-2 with prefetch to overlap the uniform edge loads with
    // the dependent row gathers
    for (; e + 1 < end; e += 2) {
        int   s0 = ssrc[e];
        int   s1 = ssrc[e + 1];
        float w0 = sw[e];
        float w1 = sw[e + 1];
        float v0 = x[(size_t)s0 * D_FEAT + lane];
        float v1 = x[(size_t)s1 * D_FEAT + lane];
        acc = fmaf(w0, v0, acc);
        acc = fmaf(w1, v1, acc);
    }
    if (e < end) {
        int   s0 = ssrc[e];
        float w0 = sw[e];
        acc = fmaf(w0, x[(size_t)s0 * D_FEAT + lane], acc);
    }
    float f = acc;
    if (isnan(f)) f = 0.0f;
    f = fminf(fmaxf(f, -CLAMP_V), CLAMP_V);
    out[(size_t)node * D_FEAT + lane] = f;
}

// ---------------------------------------------------------------------------
// Fallback (round-1 atomic path) if ws_size is insufficient.
// ---------------------------------------------------------------------------
__global__ void zero_kernel(float4* __restrict__ out, int n4) {
    int i = blockIdx.x * blockDim.x + threadIdx.x;
    if (i < n4) out[i] = make_float4(0.f, 0.f, 0.f, 0.f);
}

__global__ void scatter_kernel(const float* __restrict__ x,
                               const int* __restrict__ esrc,
                               const int* __restrict__ edst,
                               const float* __restrict__ ew,
                               float* __restrict__ out) {
    long long tid = (long long)blockIdx.x * blockDim.x + threadIdx.x;
    int edge = (int)(tid >> 4);
    int q    = (int)(tid & 15);
    if (edge >= N_EDGES) return;
    int   s = esrc[edge];
    int   d = edst[edge];
    float w = ew[edge];
    const float4* xrow = (const float4*)(x + (size_t)s * D_FEAT);
    float4 v = xrow[q];
    float* orow = out + (size_t)d * D_FEAT + q * 4;
    atomicAdd(orow + 0, w * v.x);
    atomicAdd(orow + 1, w * v.y);
    atomicAdd(orow + 2, w * v.z);
    atomicAdd(orow + 3, w * v.w);
}

__global__ void epilogue_kernel(float4* __restrict__ out, int n4) {
    int i = blockIdx.x * blockDim.x + threadIdx.x;
    if (i >= n4) return;
    float4 v = out[i];
    float* p = &v.x;
#pragma unroll
    for (int k = 0; k < 4; ++k) {
        float f = p[k];
        if (isnan(f)) f = 0.0f;
        f = fminf(fmaxf(f, -CLAMP_V), CLAMP_V);
        p[k] = f;
    }
    out[i] = v;
}

extern "C" void kernel_launch(void* const* d_in, const int* in_sizes, int n_in,
                              void* d_out, int out_size, void* d_ws, size_t ws_size,
                              hipStream_t stream) {
    const float* x    = (const float*)d_in[1];
    const int*   esrc = (const int*)d_in[2];
    const int*   edst = (const int*)d_in[3];
    const float* ew   = (const float*)d_in[4];
    float*       out  = (float*)d_out;

    // workspace carve
    size_t need = (size_t)(N_NODES            // counts
                  + (N_NODES + 1)             // starts
                  + N_NODES                   // cursors
                  + N_EDGES) * sizeof(int)    // ssrc
                + (size_t)N_EDGES * sizeof(float);  // sw

    if (ws_size >= need) {
        int*   counts  = (int*)d_ws;
        int*   starts  = counts + N_NODES;
        int*   cursors = starts + (N_NODES + 1);
        int*   ssrc    = cursors + N_NODES;
        float* sw      = (float*)(ssrc + N_EDGES);

        zero_counts_kernel<<<(N_NODES + 255) / 256, 256, 0, stream>>>(counts, N_NODES);
        hist_kernel<<<(N_EDGES + 255) / 256, 256, 0, stream>>>(edst, counts);
        scan_kernel<<<1, SCAN_T, 0, stream>>>(counts, starts, cursors);
        bucket_kernel<<<(N_EDGES + 255) / 256, 256, 0, stream>>>(esrc, edst, ew,
                                                                 cursors, ssrc, sw);
        {
            const int waves_per_block = 4;              // 256 threads
            int blocks = (N_NODES + waves_per_block - 1) / waves_per_block;
            gather_kernel<<<blocks, waves_per_block * 64, 0, stream>>>(x, ssrc, sw,
                                                                       starts, out);
        }
    } else {
        const int n4 = N_NODES * D_FEAT / 4;
        zero_kernel<<<(n4 + 255) / 256, 256, 0, stream>>>((float4*)out, n4);
        long long total = (long long)N_EDGES * 16;
        scatter_kernel<<<(int)((total + 255) / 256), 256, 0, stream>>>(x, esrc, edst, ew, out);
        epilogue_kernel<<<(n4 + 255) / 256, 256, 0, stream>>>((float4*)out, n4);
    }
}